// Round 5
// baseline (593.560 us; speedup 1.0000x reference)
//
#include <hip/hip_runtime.h>
#include <hip/hip_cooperative_groups.h>
#include <cstdint>
#include <math.h>

namespace cg = cooperative_groups;

#define N 6144
#define FIN 128
#define FH 64
#define NHEADS 4
#define NC 16
#define CAP 512
#define ALPHA 0.2f
#define NB 512           // cooperative grid blocks (2/CU used, 4/CU capacity)
#define RPB 12           // rows/nodes per block in fused P1/P2 (N/NB)
#define NT 16            // fallback k_hgemm tile

__device__ __forceinline__ float wave_sum(float v) {
    #pragma unroll
    for (int off = 32; off >= 1; off >>= 1) v += __shfl_xor(v, off);
    return v;
}
__device__ __forceinline__ float wave_max(float v) {
    #pragma unroll
    for (int off = 32; off >= 1; off >>= 1) v = fmaxf(v, __shfl_xor(v, off));
    return v;
}

// ======================= fused cooperative megakernel =======================
// P0 weff -> P1 hGEMM+s/t -> P2 row scan + hidden attn + oGEMM -> P3 out attn
__global__ void __launch_bounds__(256, 4)
k_fused(const float* __restrict__ adj, const float* __restrict__ feat,
        const float* __restrict__ W0, const float* __restrict__ a1,
        const float* __restrict__ a2, const float* __restrict__ wout,
        const float* __restrict__ a1o, const float* __restrict__ a2o,
        float* __restrict__ weff, float* __restrict__ hfeat,
        float* __restrict__ sb, float* __restrict__ tb,
        float* __restrict__ h2, float* __restrict__ s2, float* __restrict__ t2,
        int* __restrict__ cols, int* __restrict__ deg, float* __restrict__ out)
{
    cg::grid_group grid = cg::this_grid();
    int tid = threadIdx.x, lane = tid & 63, h = tid >> 6;
    int b = blockIdx.x;

    __shared__ float fl[RPB * FIN];          // 6 KB
    __shared__ int lidx[CAP];                // 2 KB
    __shared__ float xrow[NHEADS * FH];      // 1 KB
    __shared__ int cnt;

    // ---------------- P0: weff (64 elements per block) ----------------
    if (tid < 64) {
        int idx = b * 64 + tid;              // h*8192 + k*64 + f
        int f = idx & 63, k = (idx >> 6) & 127, hh = idx >> 13;
        const float* base = W0 + (size_t)hh * 512 * 64;
        float s = 0.f;
        #pragma unroll
        for (int r = 0; r < 4; r++) s += base[(size_t)(r * 128 + k) * 64 + f];
        weff[idx] = s;
    }
    grid.sync();

    // ---------------- P1: hGEMM + s/t (12 nodes/block, wave = head) ----------------
    {
        int n0 = b * RPB;
        for (int idx = tid; idx < RPB * FIN; idx += 256)
            fl[idx] = feat[(size_t)n0 * FIN + idx];
        __syncthreads();
        const float* wcol = weff + (size_t)h * FIN * FH + lane;
        float acc[RPB];
        #pragma unroll
        for (int nn = 0; nn < RPB; nn++) acc[nn] = 0.f;
        for (int k = 0; k < FIN; k++) {
            float w = wcol[(size_t)k * FH];
            #pragma unroll
            for (int nn = 0; nn < RPB; nn++) acc[nn] = fmaf(fl[nn * FIN + k], w, acc[nn]);
        }
        float a1v = a1[h * FH + lane], a2v = a2[h * FH + lane];
        #pragma unroll
        for (int nn = 0; nn < RPB; nn++) {
            hfeat[((size_t)h * N + (n0 + nn)) * FH + lane] = acc[nn];
            float s = wave_sum(acc[nn] * a1v);
            float t = wave_sum(acc[nn] * a2v);
            if (lane == 0) { sb[h * N + n0 + nn] = s; tb[h * N + n0 + nn] = t; }
        }
    }
    grid.sync();

    // ---------------- P2: per-row scan + hidden attention + oGEMM ----------------
    unsigned long long lmask = (1ull << lane) - 1ull;
    for (int r = 0; r < RPB; r++) {
        int i = b * RPB + r;
        if (tid == 0) cnt = 0;
        __syncthreads();
        const float4* rowv = (const float4*)(adj + (size_t)i * N);
        float4 rv[6];
        #pragma unroll
        for (int it = 0; it < 6; it++) rv[it] = rowv[it * 256 + tid];
        #pragma unroll
        for (int it = 0; it < 6; it++) {
            int jb = (it * 256 + tid) * 4;
            bool p[4] = {rv[it].x != 0.f, rv[it].y != 0.f, rv[it].z != 0.f, rv[it].w != 0.f};
            #pragma unroll
            for (int c = 0; c < 4; c++) {
                unsigned long long mm = __ballot(p[c]);
                int tot = __popcll(mm);
                if (tot) {
                    int prefix = __popcll(mm & lmask);
                    int wb;
                    if (lane == 0) wb = atomicAdd(&cnt, tot);
                    wb = __shfl(wb, 0);
                    int pos = wb + prefix;
                    if (p[c] && pos < CAP) lidx[pos] = jb + c;
                }
            }
        }
        __syncthreads();
        int d = cnt;
        if (tid == 0) deg[i] = d;
        for (int t = tid; t < min(d, CAP); t += 256) cols[(size_t)i * CAP + t] = lidx[t];

        int mode = (d == 0) ? 1 : (d > CAP ? 2 : 0);
        int count = (mode == 0) ? d : N;
        const float* trow = tb + (size_t)h * N;
        const float* hrow = hfeat + (size_t)h * N * FH;
        float si = sb[h * N + i];
        int q = lane >> 4, fo = (lane & 15) * 4;
        float m = -INFINITY, l = 0.f;
        float4 acc = {0.f, 0.f, 0.f, 0.f};
        for (int base = 0; base < count; base += 64) {
            int idx = base + lane;
            int j = 0; float lr = -INFINITY;
            if (idx < count) {
                j = (mode == 0) ? lidx[idx] : idx;
                bool ok = (mode != 2) || (adj[(size_t)i * N + j] != 0.f);
                if (ok) {
                    float z = si + trow[j];
                    lr = (z >= 0.f) ? z : ALPHA * z;
                }
            }
            float mc = wave_max(lr);
            float mn = fmaxf(m, mc);
            if (mn == -INFINITY) continue;
            float scale = (m == -INFINITY) ? 0.f : expf(m - mn);
            float w = (lr == -INFINITY) ? 0.f : expf(lr - mn);
            l = l * scale + wave_sum(w);
            acc.x *= scale; acc.y *= scale; acc.z *= scale; acc.w *= scale;
            int cn = min(64, count - base);
            #pragma unroll 4
            for (int bb = 0; bb < cn; bb += 4) {
                float wb = __shfl(w, bb + q);
                int jn = __shfl(j, bb + q);
                float4 hv = *(const float4*)(hrow + (size_t)jn * FH + fo);
                acc.x = fmaf(wb, hv.x, acc.x);
                acc.y = fmaf(wb, hv.y, acc.y);
                acc.z = fmaf(wb, hv.z, acc.z);
                acc.w = fmaf(wb, hv.w, acc.w);
            }
            m = mn;
        }
        #pragma unroll
        for (int off = 16; off <= 32; off <<= 1) {
            acc.x += __shfl_xor(acc.x, off);
            acc.y += __shfl_xor(acc.y, off);
            acc.z += __shfl_xor(acc.z, off);
            acc.w += __shfl_xor(acc.w, off);
        }
        if (lane < 16) {
            float linv = 1.f / l;
            float4 o;
            o.x = acc.x * linv; o.y = acc.y * linv; o.z = acc.z * linv; o.w = acc.w * linv;
            o.x = (o.x > 0.f) ? o.x : expm1f(o.x);
            o.y = (o.y > 0.f) ? o.y : expm1f(o.y);
            o.z = (o.z > 0.f) ? o.z : expm1f(o.z);
            o.w = (o.w > 0.f) ? o.w : expm1f(o.w);
            *(float4*)(xrow + h * FH + fo) = o;
        }
        __syncthreads();
        if (h == 0) {
            int f = lane & 15, part = lane >> 4;
            float dot = 0.f;
            #pragma unroll
            for (int k = 0; k < 64; k++)
                dot = fmaf(xrow[part * 64 + k], wout[(size_t)(part * 64 + k) * NC + f], dot);
            dot += __shfl_xor(dot, 16);
            dot += __shfl_xor(dot, 32);
            if (lane < NC) h2[(size_t)i * NC + lane] = dot;
            float sv = (lane < NC) ? dot * a1o[lane] : 0.f;
            float tv = (lane < NC) ? dot * a2o[lane] : 0.f;
            sv = wave_sum(sv); tv = wave_sum(tv);
            if (lane == 0) { s2[i] = sv; t2[i] = tv; }
        }
    }
    grid.sync();

    // ---------------- P3: output attention + elu + class softmax ----------------
    for (int i = b * NHEADS + h; i < N; i += NB * NHEADS) {
        int d = deg[i];
        int mode = (d == 0) ? 1 : (d > CAP ? 2 : 0);
        int count = (mode == 0) ? d : N;
        const int* crow = cols + (size_t)i * CAP;
        float si = s2[i];
        int f = lane & 15, q = lane >> 4;
        float m = -INFINITY, l = 0.f, acc = 0.f;
        for (int base = 0; base < count; base += 64) {
            int idx = base + lane;
            int j = 0; float lr = -INFINITY;
            if (idx < count) {
                j = (mode == 0) ? crow[idx] : idx;
                bool ok = (mode != 2) || (adj[(size_t)i * N + j] != 0.f);
                if (ok) {
                    float z = si + t2[j];
                    lr = (z >= 0.f) ? z : ALPHA * z;
                }
            }
            float mc = wave_max(lr);
            float mn = fmaxf(m, mc);
            if (mn == -INFINITY) continue;
            float scale = (m == -INFINITY) ? 0.f : expf(m - mn);
            float wv = (lr == -INFINITY) ? 0.f : expf(lr - mn);
            l = l * scale + wave_sum(wv);
            acc *= scale;
            int cn = min(64, count - base);
            #pragma unroll 4
            for (int bb = 0; bb < cn; bb += 4) {
                float wb = __shfl(wv, bb + q);
                int jn = __shfl(j, bb + q);
                acc = fmaf(wb, h2[(size_t)jn * NC + f], acc);
            }
            m = mn;
        }
        acc += __shfl_xor(acc, 16);
        acc += __shfl_xor(acc, 32);
        float o = acc / l;
        o = (o > 0.f) ? o : expm1f(o);
        float mv = (lane < NC) ? o : -INFINITY;
        float mx = wave_max(mv);
        float e = (lane < NC) ? expf(o - mx) : 0.f;
        float se = wave_sum(e);
        if (lane < NC) out[(size_t)i * NC + lane] = e / se;
    }
}

// ======================= fallback path (R3, known-good) =======================
__global__ void k_reduce_w(const float* __restrict__ W0, float* __restrict__ weff) {
    int idx = blockIdx.x * 256 + threadIdx.x;
    if (idx >= NHEADS * FIN * FH) return;
    int f = idx & 63, k = (idx >> 6) & 127, h = idx >> 13;
    const float* base = W0 + (size_t)h * 512 * 64;
    float s = 0.f;
    #pragma unroll
    for (int r = 0; r < 4; r++) s += base[(size_t)(r * 128 + k) * 64 + f];
    weff[idx] = s;
}

__global__ void k_hgemm(const float* __restrict__ feat, const float* __restrict__ weff,
                        const float* __restrict__ a1, const float* __restrict__ a2,
                        float* __restrict__ hfeat, float* __restrict__ sb,
                        float* __restrict__ tb) {
    __shared__ float fl[NT * FIN];
    int tid = threadIdx.x;
    int n0 = blockIdx.x * NT;
    for (int idx = tid; idx < NT * FIN; idx += 256) fl[idx] = feat[(size_t)n0 * FIN + idx];
    __syncthreads();
    int f = tid & 63, h = tid >> 6;
    const float* wcol = weff + (size_t)h * FIN * FH + f;
    float acc[NT];
    #pragma unroll
    for (int nn = 0; nn < NT; nn++) acc[nn] = 0.f;
    for (int k = 0; k < FIN; k++) {
        float w = wcol[(size_t)k * FH];
        #pragma unroll
        for (int nn = 0; nn < NT; nn++) acc[nn] = fmaf(fl[nn * FIN + k], w, acc[nn]);
    }
    float a1v = a1[h * FH + f], a2v = a2[h * FH + f];
    #pragma unroll
    for (int nn = 0; nn < NT; nn++) {
        hfeat[((size_t)h * N + (n0 + nn)) * FH + f] = acc[nn];
        float s = wave_sum(acc[nn] * a1v);
        float t = wave_sum(acc[nn] * a2v);
        if ((tid & 63) == 0) { sb[h * N + n0 + nn] = s; tb[h * N + n0 + nn] = t; }
    }
}

__global__ void k_row(const float* __restrict__ adj, const float* __restrict__ hfeat,
                      const float* __restrict__ sb, const float* __restrict__ tb,
                      const float* __restrict__ wout, const float* __restrict__ a1o,
                      const float* __restrict__ a2o,
                      int* __restrict__ cols, int* __restrict__ deg,
                      float* __restrict__ h2, float* __restrict__ s2,
                      float* __restrict__ t2) {
    int i = blockIdx.x;
    int tid = threadIdx.x;
    int lane = tid & 63, h = tid >> 6;
    __shared__ int lidx[CAP];
    __shared__ float xrow[NHEADS * FH];
    __shared__ int cnt;
    if (tid == 0) cnt = 0;
    __syncthreads();
    const float4* rowv = (const float4*)(adj + (size_t)i * N);
    float4 rv[6];
    #pragma unroll
    for (int it = 0; it < 6; it++) rv[it] = rowv[it * 256 + tid];
    unsigned long long lmask = (1ull << lane) - 1ull;
    #pragma unroll
    for (int it = 0; it < 6; it++) {
        int jb = (it * 256 + tid) * 4;
        bool p[4] = {rv[it].x != 0.f, rv[it].y != 0.f, rv[it].z != 0.f, rv[it].w != 0.f};
        #pragma unroll
        for (int c = 0; c < 4; c++) {
            unsigned long long mm = __ballot(p[c]);
            int tot = __popcll(mm);
            if (tot) {
                int prefix = __popcll(mm & lmask);
                int wb;
                if (lane == 0) wb = atomicAdd(&cnt, tot);
                wb = __shfl(wb, 0);
                int pos = wb + prefix;
                if (p[c] && pos < CAP) lidx[pos] = jb + c;
            }
        }
    }
    __syncthreads();
    int d = cnt;
    if (tid == 0) deg[i] = d;
    for (int t = tid; t < min(d, CAP); t += 256) cols[(size_t)i * CAP + t] = lidx[t];

    int mode = (d == 0) ? 1 : (d > CAP ? 2 : 0);
    int count = (mode == 0) ? d : N;
    const float* trow = tb + (size_t)h * N;
    const float* hrow = hfeat + (size_t)h * N * FH;
    float si = sb[h * N + i];
    int q = lane >> 4, fo = (lane & 15) * 4;
    float m = -INFINITY, l = 0.f;
    float4 acc = {0.f, 0.f, 0.f, 0.f};
    for (int base = 0; base < count; base += 64) {
        int idx = base + lane;
        int j = 0; float lr = -INFINITY;
        if (idx < count) {
            j = (mode == 0) ? lidx[idx] : idx;
            bool ok = (mode != 2) || (adj[(size_t)i * N + j] != 0.f);
            if (ok) {
                float z = si + trow[j];
                lr = (z >= 0.f) ? z : ALPHA * z;
            }
        }
        float mc = wave_max(lr);
        float mn = fmaxf(m, mc);
        if (mn == -INFINITY) continue;
        float scale = (m == -INFINITY) ? 0.f : expf(m - mn);
        float w = (lr == -INFINITY) ? 0.f : expf(lr - mn);
        l = l * scale + wave_sum(w);
        acc.x *= scale; acc.y *= scale; acc.z *= scale; acc.w *= scale;
        int cn = min(64, count - base);
        #pragma unroll 4
        for (int bb = 0; bb < cn; bb += 4) {
            float wb = __shfl(w, bb + q);
            int jn = __shfl(j, bb + q);
            float4 hv = *(const float4*)(hrow + (size_t)jn * FH + fo);
            acc.x = fmaf(wb, hv.x, acc.x);
            acc.y = fmaf(wb, hv.y, acc.y);
            acc.z = fmaf(wb, hv.z, acc.z);
            acc.w = fmaf(wb, hv.w, acc.w);
        }
        m = mn;
    }
    #pragma unroll
    for (int off = 16; off <= 32; off <<= 1) {
        acc.x += __shfl_xor(acc.x, off);
        acc.y += __shfl_xor(acc.y, off);
        acc.z += __shfl_xor(acc.z, off);
        acc.w += __shfl_xor(acc.w, off);
    }
    if (lane < 16) {
        float linv = 1.f / l;
        float4 o;
        o.x = acc.x * linv; o.y = acc.y * linv; o.z = acc.z * linv; o.w = acc.w * linv;
        o.x = (o.x > 0.f) ? o.x : expm1f(o.x);
        o.y = (o.y > 0.f) ? o.y : expm1f(o.y);
        o.z = (o.z > 0.f) ? o.z : expm1f(o.z);
        o.w = (o.w > 0.f) ? o.w : expm1f(o.w);
        *(float4*)(xrow + h * FH + fo) = o;
    }
    __syncthreads();
    if (h == 0) {
        int f = lane & 15, part = lane >> 4;
        float dot = 0.f;
        #pragma unroll
        for (int k = 0; k < 64; k++)
            dot = fmaf(xrow[part * 64 + k], wout[(size_t)(part * 64 + k) * NC + f], dot);
        dot += __shfl_xor(dot, 16);
        dot += __shfl_xor(dot, 32);
        if (lane < NC) h2[(size_t)i * NC + lane] = dot;
        float sv = (lane < NC) ? dot * a1o[lane] : 0.f;
        float tv = (lane < NC) ? dot * a2o[lane] : 0.f;
        sv = wave_sum(sv); tv = wave_sum(tv);
        if (lane == 0) { s2[i] = sv; t2[i] = tv; }
    }
}

__global__ void k_attn_out(const float* __restrict__ h2, const float* __restrict__ s2,
                           const float* __restrict__ t2, const int* __restrict__ cols,
                           const int* __restrict__ deg, const float* __restrict__ adj,
                           float* __restrict__ out) {
    int w = threadIdx.x >> 6, lane = threadIdx.x & 63;
    int i = blockIdx.x * 4 + w;
    int d = deg[i];
    int mode = (d == 0) ? 1 : (d > CAP ? 2 : 0);
    int count = (mode == 0) ? d : N;
    const int* crow = cols + (size_t)i * CAP;
    float si = s2[i];
    int f = lane & 15, q = lane >> 4;
    float m = -INFINITY, l = 0.f, acc = 0.f;
    for (int base = 0; base < count; base += 64) {
        int idx = base + lane;
        int j = 0; float lr = -INFINITY;
        if (idx < count) {
            j = (mode == 0) ? crow[idx] : idx;
            bool ok = (mode != 2) || (adj[(size_t)i * N + j] != 0.f);
            if (ok) {
                float z = si + t2[j];
                lr = (z >= 0.f) ? z : ALPHA * z;
            }
        }
        float mc = wave_max(lr);
        float mn = fmaxf(m, mc);
        if (mn == -INFINITY) continue;
        float scale = (m == -INFINITY) ? 0.f : expf(m - mn);
        float wv = (lr == -INFINITY) ? 0.f : expf(lr - mn);
        l = l * scale + wave_sum(wv);
        acc *= scale;
        int cn = min(64, count - base);
        #pragma unroll 4
        for (int bb = 0; bb < cn; bb += 4) {
            float wb = __shfl(wv, bb + q);
            int jn = __shfl(j, bb + q);
            acc = fmaf(wb, h2[(size_t)jn * NC + f], acc);
        }
        m = mn;
    }
    acc += __shfl_xor(acc, 16);
    acc += __shfl_xor(acc, 32);
    float o = acc / l;
    o = (o > 0.f) ? o : expm1f(o);
    float mv = (lane < NC) ? o : -INFINITY;
    float mx = wave_max(mv);
    float e = (lane < NC) ? expf(o - mx) : 0.f;
    float se = wave_sum(e);
    if (lane < NC) out[(size_t)i * NC + lane] = e / se;
}

extern "C" void kernel_launch(void* const* d_in, const int* in_sizes, int n_in,
                              void* d_out, int out_size, void* d_ws, size_t ws_size,
                              hipStream_t stream) {
    const float* adj  = (const float*)d_in[0];
    const float* feat = (const float*)d_in[1];
    const float* W0   = (const float*)d_in[2];
    const float* a1_0 = (const float*)d_in[3];
    const float* a2_0 = (const float*)d_in[4];
    const float* Wout = (const float*)d_in[5];
    const float* a1o  = (const float*)d_in[6];
    const float* a2o  = (const float*)d_in[7];
    float* outp = (float*)d_out;

    float* weff  = (float*)d_ws;                 // 32768
    float* hfeat = weff + 32768;                 // 1572864
    float* sb    = hfeat + 1572864;              // 24576
    float* tb    = sb + 24576;                   // 24576
    float* h2    = tb + 24576;                   // 98304
    float* s2    = h2 + 98304;                   // 6144
    float* t2    = s2 + 6144;                    // 6144
    int*   cols  = (int*)(t2 + 6144);            // 6144*512
    int*   deg   = cols + (size_t)N * CAP;       // 6144

    void* args[] = {(void*)&adj, (void*)&feat, (void*)&W0, (void*)&a1_0, (void*)&a2_0,
                    (void*)&Wout, (void*)&a1o, (void*)&a2o,
                    (void*)&weff, (void*)&hfeat, (void*)&sb, (void*)&tb,
                    (void*)&h2, (void*)&s2, (void*)&t2,
                    (void*)&cols, (void*)&deg, (void*)&outp};
    hipError_t err = hipLaunchCooperativeKernel((const void*)k_fused, dim3(NB), dim3(256),
                                                args, 0, stream);
    if (err != hipSuccess) {
        // deterministic fallback: known-good 4-kernel path (same work every call)
        k_reduce_w<<<128, 256, 0, stream>>>(W0, weff);
        k_hgemm<<<N / NT, 256, 0, stream>>>(feat, weff, a1_0, a2_0, hfeat, sb, tb);
        k_row<<<N, 256, 0, stream>>>(adj, hfeat, sb, tb, Wout, a1o, a2o,
                                     cols, deg, h2, s2, t2);
        k_attn_out<<<N / 4, 256, 0, stream>>>(h2, s2, t2, cols, deg, adj, outp);
    }
}

// Round 6
// 266.756 us; speedup vs baseline: 2.2251x; 2.2251x over previous
//
#include <hip/hip_runtime.h>
#include <cstdint>
#include <math.h>

#define N 6144
#define FIN 128
#define FH 64
#define NHEADS 4
#define NC 16
#define CAP 512
#define ALPHA 0.2f
#define NT 16

__device__ __forceinline__ float wave_sum(float v) {
    #pragma unroll
    for (int off = 32; off >= 1; off >>= 1) v += __shfl_xor(v, off);
    return v;
}
__device__ __forceinline__ float wave_max(float v) {
    #pragma unroll
    for (int off = 32; off >= 1; off >>= 1) v = fmaxf(v, __shfl_xor(v, off));
    return v;
}

// Weff[h][k][f] = sum_r W0[h][r*128+k][f]   (x = tile(feature,(1,4)) collapse)
__global__ void k_reduce_w(const float* __restrict__ W0, float* __restrict__ weff) {
    int idx = blockIdx.x * 256 + threadIdx.x;
    if (idx >= NHEADS * FIN * FH) return;
    int f = idx & 63, k = (idx >> 6) & 127, h = idx >> 13;
    const float* base = W0 + (size_t)h * 512 * 64;
    float s = 0.f;
    #pragma unroll
    for (int r = 0; r < 4; r++) s += base[(size_t)(r * 128 + k) * 64 + f];
    weff[idx] = s;
}

// hfeat[h][n][f] = feature[n] . Weff[h][:,f]; fused s = h.a1, t = h.a2
__global__ void k_hgemm(const float* __restrict__ feat, const float* __restrict__ weff,
                        const float* __restrict__ a1, const float* __restrict__ a2,
                        float* __restrict__ hfeat, float* __restrict__ sb,
                        float* __restrict__ tb) {
    __shared__ float fl[NT * FIN];
    int tid = threadIdx.x;
    int n0 = blockIdx.x * NT;
    for (int idx = tid; idx < NT * FIN; idx += 256) fl[idx] = feat[(size_t)n0 * FIN + idx];
    __syncthreads();
    int f = tid & 63, h = tid >> 6;                  // one wave per head
    const float* wcol = weff + (size_t)h * FIN * FH + f;
    float acc[NT];
    #pragma unroll
    for (int nn = 0; nn < NT; nn++) acc[nn] = 0.f;
    for (int k = 0; k < FIN; k++) {
        float w = wcol[(size_t)k * FH];
        #pragma unroll
        for (int nn = 0; nn < NT; nn++) acc[nn] = fmaf(fl[nn * FIN + k], w, acc[nn]);
    }
    float a1v = a1[h * FH + f], a2v = a2[h * FH + f];
    #pragma unroll
    for (int nn = 0; nn < NT; nn++) {
        hfeat[((size_t)h * N + (n0 + nn)) * FH + f] = acc[nn];
        float s = wave_sum(acc[nn] * a1v);
        float t = wave_sum(acc[nn] * a2v);
        if ((tid & 63) == 0) { sb[h * N + n0 + nn] = s; tb[h * N + n0 + nn] = t; }
    }
}

// Per-row: adj scan -> prefix-sum compaction into LDS -> per-head online-softmax
// aggregation -> elu -> x1 row in LDS -> fused output GEMM (h2, s2, t2).
__global__ void k_row(const float* __restrict__ adj, const float* __restrict__ hfeat,
                      const float* __restrict__ sb, const float* __restrict__ tb,
                      const float* __restrict__ wout, const float* __restrict__ a1o,
                      const float* __restrict__ a2o,
                      int* __restrict__ cols, int* __restrict__ deg,
                      float* __restrict__ h2, float* __restrict__ s2,
                      float* __restrict__ t2) {
    int i = blockIdx.x;
    int tid = threadIdx.x;
    int lane = tid & 63, h = tid >> 6;
    __shared__ int lidx[CAP];
    __shared__ float xrow[NHEADS * FH];
    __shared__ int wtot[4];

    // ---- scan: 6 hoisted float4 loads, single block-wide prefix compaction ----
    const float4* rowv = (const float4*)(adj + (size_t)i * N);
    float4 rv[6];
    #pragma unroll
    for (int it = 0; it < 6; it++) rv[it] = rowv[it * 256 + tid];

    unsigned int bits = 0;
    int c = 0;
    #pragma unroll
    for (int it = 0; it < 6; it++) {
        bool p0 = rv[it].x != 0.f, p1 = rv[it].y != 0.f;
        bool p2 = rv[it].z != 0.f, p3 = rv[it].w != 0.f;
        bits |= (unsigned)p0 << (it * 4 + 0);
        bits |= (unsigned)p1 << (it * 4 + 1);
        bits |= (unsigned)p2 << (it * 4 + 2);
        bits |= (unsigned)p3 << (it * 4 + 3);
        c += (int)p0 + (int)p1 + (int)p2 + (int)p3;
    }
    // wave inclusive scan of per-thread counts
    int inc = c;
    #pragma unroll
    for (int off = 1; off < 64; off <<= 1) {
        int v = __shfl_up(inc, off);
        if (lane >= off) inc += v;
    }
    if (lane == 63) wtot[h] = inc;
    __syncthreads();
    int wbase = 0;
    #pragma unroll
    for (int w = 0; w < 4; w++) wbase += (w < h) ? wtot[w] : 0;
    int d = wtot[0] + wtot[1] + wtot[2] + wtot[3];
    int base = wbase + inc - c;                      // exclusive offset of this thread
    #pragma unroll
    for (int it = 0; it < 6; it++) {
        #pragma unroll
        for (int cc = 0; cc < 4; cc++) {
            if (bits & (1u << (it * 4 + cc))) {
                if (base < CAP) lidx[base] = (it * 256 + tid) * 4 + cc;
                base++;
            }
        }
    }
    __syncthreads();
    if (tid == 0) deg[i] = d;
    for (int t = tid; t < min(d, CAP); t += 256) cols[(size_t)i * CAP + t] = lidx[t];

    // ---- per-head online-softmax aggregation (quarter-wave: 4 neighbors x float4) ----
    int mode = (d == 0) ? 1 : (d > CAP ? 2 : 0);
    int count = (mode == 0) ? d : N;
    const float* trow = tb + (size_t)h * N;
    const float* hrow = hfeat + (size_t)h * N * FH;
    float si = sb[h * N + i];
    int q = lane >> 4, fo = (lane & 15) * 4;
    float m = -INFINITY, l = 0.f;
    float4 acc = {0.f, 0.f, 0.f, 0.f};
    for (int bs = 0; bs < count; bs += 64) {
        int idx = bs + lane;
        int j = 0; float lr = -INFINITY;
        if (idx < count) {
            j = (mode == 0) ? lidx[idx] : idx;
            bool ok = (mode != 2) || (adj[(size_t)i * N + j] != 0.f);
            if (ok) {
                float z = si + trow[j];
                lr = (z >= 0.f) ? z : ALPHA * z;
            }
        }
        float mc = wave_max(lr);
        float mn = fmaxf(m, mc);
        if (mn == -INFINITY) continue;               // wave-uniform
        float scale = (m == -INFINITY) ? 0.f : expf(m - mn);
        float w = (lr == -INFINITY) ? 0.f : expf(lr - mn);
        l = l * scale + wave_sum(w);
        acc.x *= scale; acc.y *= scale; acc.z *= scale; acc.w *= scale;
        int cn = min(64, count - bs);
        #pragma unroll 4
        for (int bb = 0; bb < cn; bb += 4) {
            float wb = __shfl(w, bb + q);
            int jn = __shfl(j, bb + q);
            float4 hv = *(const float4*)(hrow + (size_t)jn * FH + fo);
            acc.x = fmaf(wb, hv.x, acc.x);
            acc.y = fmaf(wb, hv.y, acc.y);
            acc.z = fmaf(wb, hv.z, acc.z);
            acc.w = fmaf(wb, hv.w, acc.w);
        }
        m = mn;
    }
    #pragma unroll
    for (int off = 16; off <= 32; off <<= 1) {
        acc.x += __shfl_xor(acc.x, off);
        acc.y += __shfl_xor(acc.y, off);
        acc.z += __shfl_xor(acc.z, off);
        acc.w += __shfl_xor(acc.w, off);
    }
    if (lane < 16) {
        float linv = 1.f / l;
        float4 o;
        o.x = acc.x * linv; o.y = acc.y * linv; o.z = acc.z * linv; o.w = acc.w * linv;
        o.x = (o.x > 0.f) ? o.x : expm1f(o.x);
        o.y = (o.y > 0.f) ? o.y : expm1f(o.y);
        o.z = (o.z > 0.f) ? o.z : expm1f(o.z);
        o.w = (o.w > 0.f) ? o.w : expm1f(o.w);
        *(float4*)(xrow + h * FH + fo) = o;          // x1 row stays in LDS
    }
    __syncthreads();

    // ---- fused output GEMM: h2[i] = xrow @ Wout; s2/t2 (wave 0) ----
    if (h == 0) {
        int f = lane & 15, part = lane >> 4;
        float dot = 0.f;
        #pragma unroll
        for (int k = 0; k < 64; k++)
            dot = fmaf(xrow[part * 64 + k], wout[(size_t)(part * 64 + k) * NC + f], dot);
        dot += __shfl_xor(dot, 16);
        dot += __shfl_xor(dot, 32);
        if (lane < NC) h2[(size_t)i * NC + lane] = dot;
        float sv = (lane < NC) ? dot * a1o[lane] : 0.f;
        float tv = (lane < NC) ? dot * a2o[lane] : 0.f;
        sv = wave_sum(sv); tv = wave_sum(tv);
        if (lane == 0) { s2[i] = sv; t2[i] = tv; }
    }
}

// Output-layer attention + elu + class softmax. One wave per row, quarter-wave gather.
__global__ void k_attn_out(const float* __restrict__ h2, const float* __restrict__ s2,
                           const float* __restrict__ t2, const int* __restrict__ cols,
                           const int* __restrict__ deg, const float* __restrict__ adj,
                           float* __restrict__ out) {
    int w = threadIdx.x >> 6, lane = threadIdx.x & 63;
    int i = blockIdx.x * 4 + w;
    int d = deg[i];
    int mode = (d == 0) ? 1 : (d > CAP ? 2 : 0);
    int count = (mode == 0) ? d : N;
    const int* crow = cols + (size_t)i * CAP;
    float si = s2[i];
    int f = lane & 15, q = lane >> 4;
    float m = -INFINITY, l = 0.f, acc = 0.f;
    for (int bs = 0; bs < count; bs += 64) {
        int idx = bs + lane;
        int j = 0; float lr = -INFINITY;
        if (idx < count) {
            j = (mode == 0) ? crow[idx] : idx;
            bool ok = (mode != 2) || (adj[(size_t)i * N + j] != 0.f);
            if (ok) {
                float z = si + t2[j];
                lr = (z >= 0.f) ? z : ALPHA * z;
            }
        }
        float mc = wave_max(lr);
        float mn = fmaxf(m, mc);
        if (mn == -INFINITY) continue;
        float scale = (m == -INFINITY) ? 0.f : expf(m - mn);
        float wv = (lr == -INFINITY) ? 0.f : expf(lr - mn);
        l = l * scale + wave_sum(wv);
        acc *= scale;
        int cn = min(64, count - bs);
        #pragma unroll 4
        for (int bb = 0; bb < cn; bb += 4) {
            float wb = __shfl(wv, bb + q);
            int jn = __shfl(j, bb + q);
            acc = fmaf(wb, h2[(size_t)jn * NC + f], acc);
        }
        m = mn;
    }
    acc += __shfl_xor(acc, 16);
    acc += __shfl_xor(acc, 32);
    float o = acc / l;
    o = (o > 0.f) ? o : expm1f(o);                   // elu
    float mv = (lane < NC) ? o : -INFINITY;
    float mx = wave_max(mv);
    float e = (lane < NC) ? expf(o - mx) : 0.f;
    float se = wave_sum(e);
    if (lane < NC) out[(size_t)i * NC + lane] = e / se;
}

extern "C" void kernel_launch(void* const* d_in, const int* in_sizes, int n_in,
                              void* d_out, int out_size, void* d_ws, size_t ws_size,
                              hipStream_t stream) {
    const float* adj  = (const float*)d_in[0];   // [N,N]
    const float* feat = (const float*)d_in[1];   // [N,128]
    const float* W0   = (const float*)d_in[2];   // [4,512,64]
    const float* a1_0 = (const float*)d_in[3];   // [4,64]
    const float* a2_0 = (const float*)d_in[4];   // [4,64]
    const float* Wout = (const float*)d_in[5];   // [256,16]
    const float* a1o  = (const float*)d_in[6];   // [16]
    const float* a2o  = (const float*)d_in[7];   // [16]
    float* outp = (float*)d_out;                 // [N,16]

    float* weff  = (float*)d_ws;                 // 32768
    float* hfeat = weff + 32768;                 // 4*6144*64 = 1572864
    float* sb    = hfeat + 1572864;              // 24576
    float* tb    = sb + 24576;                   // 24576
    float* h2    = tb + 24576;                   // 98304
    float* s2    = h2 + 98304;                   // 6144
    float* t2    = s2 + 6144;                    // 6144
    int*   cols  = (int*)(t2 + 6144);            // 6144*512
    int*   deg   = cols + (size_t)N * CAP;       // 6144

    k_reduce_w<<<128, 256, 0, stream>>>(W0, weff);
    k_hgemm<<<N / NT, 256, 0, stream>>>(feat, weff, a1_0, a2_0, hfeat, sb, tb);
    k_row<<<N, 256, 0, stream>>>(adj, hfeat, sb, tb, Wout, a1o, a2o,
                                 cols, deg, h2, s2, t2);
    k_attn_out<<<N / 4, 256, 0, stream>>>(h2, s2, t2, cols, deg, adj, outp);
}